// Round 6
// baseline (218.241 us; speedup 1.0000x reference)
//
#include <hip/hip_runtime.h>
#include <hip/hip_bf16.h>
#include <math.h>

#define NTIME 20
#define V 128
#define F 128
constexpr float ALPHA = 0.2f;

// ---------------- kernel 0: Wa[s] = W @ a_s  (128x128 each, f32) ----------------
__global__ __launch_bounds__(128) void k_wa(const float* __restrict__ W,
                                            const float* __restrict__ a,
                                            float* __restrict__ Wa) {
  const int i = blockIdx.x;
  const int s = blockIdx.y;
  const int k = threadIdx.x;
  __shared__ float wrow[F];
  wrow[k] = W[i * F + k];
  __syncthreads();
  const float* as = a + s * F * F;
  float acc = 0.f;
#pragma unroll 8
  for (int m = 0; m < F; ++m) acc += wrow[m] * as[m * F + k];
  Wa[(s * F + i) * F + k] = acc;
}

// ---------------- kernel 1: [Wh|E1|E2] = h @ [W|Wa1|Wa2] ----------------
__global__ __launch_bounds__(256) void k_gemm(const float* __restrict__ h,
                                              const float* __restrict__ W,
                                              const float* __restrict__ Wa,
                                              float* __restrict__ Wh,
                                              float* __restrict__ E1,
                                              float* __restrict__ E2) {
  __shared__ float Alds[64][129];
  __shared__ float Blds[128][64];
  const int tid = threadIdx.x;
  const int rb = blockIdx.x * 64;
  const int matc = blockIdx.y >> 1;
  const int cb = (blockIdx.y & 1) * 64;

#pragma unroll
  for (int p = 0; p < 8; ++p) {
    int id = tid + p * 256;
    int row = id >> 5;
    int c0 = (id & 31) * 4;
    float4 v = *reinterpret_cast<const float4*>(&h[(rb + row) * F + c0]);
    Alds[row][c0 + 0] = v.x; Alds[row][c0 + 1] = v.y;
    Alds[row][c0 + 2] = v.z; Alds[row][c0 + 3] = v.w;
  }
  const float* src = (matc == 0) ? W : (Wa + (matc - 1) * F * F);
#pragma unroll
  for (int p = 0; p < 8; ++p) {
    int id = tid + p * 256;
    int k = id >> 4;
    int c0 = (id & 15) * 4;
    float4 v = *reinterpret_cast<const float4*>(&src[k * F + cb + c0]);
    Blds[k][c0 + 0] = v.x; Blds[k][c0 + 1] = v.y;
    Blds[k][c0 + 2] = v.z; Blds[k][c0 + 3] = v.w;
  }
  __syncthreads();

  const int tx = tid & 15;
  const int ty = tid >> 4;
  float acc[4][4] = {};
#pragma unroll 4
  for (int k = 0; k < 128; ++k) {
    float4 bv = *reinterpret_cast<const float4*>(&Blds[k][tx * 4]);
    float a0 = Alds[ty * 4 + 0][k];
    float a1 = Alds[ty * 4 + 1][k];
    float a2 = Alds[ty * 4 + 2][k];
    float a3 = Alds[ty * 4 + 3][k];
    acc[0][0] += a0 * bv.x; acc[0][1] += a0 * bv.y; acc[0][2] += a0 * bv.z; acc[0][3] += a0 * bv.w;
    acc[1][0] += a1 * bv.x; acc[1][1] += a1 * bv.y; acc[1][2] += a1 * bv.z; acc[1][3] += a1 * bv.w;
    acc[2][0] += a2 * bv.x; acc[2][1] += a2 * bv.y; acc[2][2] += a2 * bv.z; acc[2][3] += a2 * bv.w;
    acc[3][0] += a3 * bv.x; acc[3][1] += a3 * bv.y; acc[3][2] += a3 * bv.z; acc[3][3] += a3 * bv.w;
  }

  float* Dp = (matc == 0) ? Wh : ((matc == 1) ? E1 : E2);
  const int gr0 = rb + ty * 4;
  const int c0 = cb + tx * 4;
#pragma unroll
  for (int i = 0; i < 4; ++i) {
    float4 v;
    v.x = acc[i][0]; v.y = acc[i][1]; v.z = acc[i][2]; v.w = acc[i][3];
    *reinterpret_cast<float4*>(&Dp[(gr0 + i) * F + c0]) = v;
  }
}

// ---------- kernel 2a: softmax denominators + h' + elu (no att stores) ----------
// Block 256 = 4 waves per (t,b) row; wave w owns j-strip [w*32, w*32+32).
// Writes out[r][*], INV[r][*] (reciprocal denominators) and UNI[r] flag.
__global__ __launch_bounds__(256) void k_attn_a(const float* __restrict__ Wh,
                                                const float* __restrict__ E1,
                                                const float* __restrict__ E2,
                                                const float* __restrict__ adj,
                                                float* __restrict__ out,
                                                float* __restrict__ INV,
                                                float* __restrict__ UNI) {
  __shared__ float sA[4][F];
  __shared__ float hA[4][F];

  const int r = blockIdx.x;               // 0..2559
  const int t = r >> 7;
  const int b = r & 127;
  const int w = threadIdx.x >> 6;
  const int lane = threadIdx.x & 63;
  const int fc = lane * 2;
  const int j0 = w * 32;

  const float* E2t = E2 + t * V * F;
  const float* Wht = Wh + t * V * F;
  const float* adjb = adj + b * V;
  const float2 e1v = *reinterpret_cast<const float2*>(E1 + r * F + fc);

  float s0 = 0.f, s1 = 0.f, h0 = 0.f, h1 = 0.f;
#pragma unroll 4
  for (int jj = 0; jj < 32; ++jj) {
    const int j = j0 + jj;
    if (adjb[j] > 0.f) {                  // wave-uniform branch
      float2 e2 = *reinterpret_cast<const float2*>(E2t + j * F + fc);
      float x0 = e1v.x + e2.x, x1 = e1v.y + e2.y;
      x0 = x0 > 0.f ? x0 : ALPHA * x0;
      x1 = x1 > 0.f ? x1 : ALPHA * x1;
      float p0 = __expf(x0), p1 = __expf(x1);
      float2 wv = *reinterpret_cast<const float2*>(Wht + j * F + fc);
      s0 += p0; s1 += p1;
      h0 += p0 * wv.x; h1 += p1 * wv.y;
    }
  }
  sA[w][fc] = s0; sA[w][fc + 1] = s1;
  hA[w][fc] = h0; hA[w][fc + 1] = h1;
  __syncthreads();

  if (w == 0) {
    const float S0 = sA[0][fc] + sA[1][fc] + sA[2][fc] + sA[3][fc];
    const float S1 = sA[0][fc + 1] + sA[1][fc + 1] + sA[2][fc + 1] + sA[3][fc + 1];
    const bool uni = (S0 == 0.f);         // all-masked row: softmax -> uniform 1/V
    const float inv0 = uni ? (1.f / (float)V) : (1.f / S0);
    const float inv1 = uni ? (1.f / (float)V) : (1.f / S1);
    float2 iv; iv.x = inv0; iv.y = inv1;
    *reinterpret_cast<float2*>(INV + r * F + fc) = iv;
    if (threadIdx.x == 0) UNI[r] = uni ? 1.f : 0.f;

    float H0, H1;
    if (uni) {
      H0 = 0.f; H1 = 0.f;
      for (int j = 0; j < V; ++j) {
        float2 wv = *reinterpret_cast<const float2*>(Wht + j * F + fc);
        H0 += wv.x; H1 += wv.y;
      }
      H0 *= inv0; H1 *= inv1;
    } else {
      H0 = (hA[0][fc] + hA[1][fc] + hA[2][fc] + hA[3][fc]) * inv0;
      H1 = (hA[0][fc + 1] + hA[1][fc + 1] + hA[2][fc + 1] + hA[3][fc + 1]) * inv1;
    }
    float2 ov;
    ov.x = H0 > 0.f ? H0 : __expf(H0) - 1.f;
    ov.y = H1 > 0.f ? H1 : __expf(H1) - 1.f;
    *reinterpret_cast<float2*>(out + r * F + fc) = ov;
  }
}

// ---------- kernel 2b: pure streaming att writer (fill-shaped) ----------
// Grid-stride over the 10,485,760 float4s of att in LINEAR order (same address
// pattern as the 6.5 TB/s harness fill). No LDS, no syncs, branchless selects.
__global__ __launch_bounds__(256) void k_attn_b(const float* __restrict__ E1,
                                                const float* __restrict__ E2,
                                                const float* __restrict__ adj,
                                                const float* __restrict__ INV,
                                                const float* __restrict__ UNI,
                                                float* __restrict__ att) {
  const int gidx = blockIdx.x * 256 + threadIdx.x;   // 0..655359
#pragma unroll 4
  for (int it = 0; it < 16; ++it) {
    const int idx = gidx + it * 655360;              // float4 index
    const int elems = idx << 2;                      // element index
    const int f0 = elems & 127;
    const int j = (elems >> 7) & 127;
    const int r = elems >> 14;
    const int b = r & 127;
    const int t = r >> 7;

    const float4 e1q = *reinterpret_cast<const float4*>(E1 + r * F + f0);
    const float4 invq = *reinterpret_cast<const float4*>(INV + r * F + f0);
    const float4 e2q = *reinterpret_cast<const float4*>(E2 + (t * V + j) * F + f0);
    const float av = adj[b * V + j];
    const float u = UNI[r];

    float x0 = e1q.x + e2q.x, x1 = e1q.y + e2q.y;
    float x2 = e1q.z + e2q.z, x3 = e1q.w + e2q.w;
    x0 = x0 > 0.f ? x0 : ALPHA * x0;
    x1 = x1 > 0.f ? x1 : ALPHA * x1;
    x2 = x2 > 0.f ? x2 : ALPHA * x2;
    x3 = x3 > 0.f ? x3 : ALPHA * x3;
    const float g = (av > 0.f) ? 1.f : 0.f;          // mask gate
    float4 o;
    o.x = __expf(x0) * invq.x * g;
    o.y = __expf(x1) * invq.y * g;
    o.z = __expf(x2) * invq.z * g;
    o.w = __expf(x3) * invq.w * g;
    if (u != 0.f) { o.x = invq.x; o.y = invq.y; o.z = invq.z; o.w = invq.w; }
    *reinterpret_cast<float4*>(att + elems) = o;
  }
}

extern "C" void kernel_launch(void* const* d_in, const int* in_sizes, int n_in,
                              void* d_out, int out_size, void* d_ws, size_t ws_size,
                              hipStream_t stream) {
  (void)in_sizes; (void)n_in; (void)out_size; (void)ws_size;
  const float* h   = (const float*)d_in[0];
  const float* adj = (const float*)d_in[1];
  const float* W   = (const float*)d_in[2];
  const float* a   = (const float*)d_in[3];

  // ws layout (f32): Wh | E1 | E2 | Wa(2*F*F) | INV | UNI
  float* Wh  = (float*)d_ws;
  float* E1  = Wh + NTIME * V * F;
  float* E2  = E1 + NTIME * V * F;
  float* Wa  = E2 + NTIME * V * F;
  float* INV = Wa + 2 * F * F;
  float* UNI = INV + NTIME * V * F;

  float* out = (float*)d_out;                    // (T, V, F)
  float* att = out + NTIME * V * F;              // (T, V, V, F)

  k_wa<<<dim3(128, 2), 128, 0, stream>>>(W, a, Wa);
  k_gemm<<<dim3(40, 6), 256, 0, stream>>>(h, W, Wa, Wh, E1, E2);
  k_attn_a<<<dim3(NTIME * V), 256, 0, stream>>>(Wh, E1, E2, adj, out, INV, UNI);
  k_attn_b<<<dim3(2560), 256, 0, stream>>>(E1, E2, adj, INV, UNI, att);
}

// Round 7
// 200.332 us; speedup vs baseline: 1.0894x; 1.0894x over previous
//
#include <hip/hip_runtime.h>
#include <hip/hip_bf16.h>
#include <math.h>

#define NTIME 20
#define V 128
#define F 128
constexpr float ALPHA = 0.2f;

// ---------------- kernel 0: Wa[s] = W @ a_s  (128x128 each, f32) ----------------
__global__ __launch_bounds__(128) void k_wa(const float* __restrict__ W,
                                            const float* __restrict__ a,
                                            float* __restrict__ Wa) {
  const int i = blockIdx.x;
  const int s = blockIdx.y;
  const int k = threadIdx.x;
  __shared__ float wrow[F];
  wrow[k] = W[i * F + k];
  __syncthreads();
  const float* as = a + s * F * F;
  float acc = 0.f;
#pragma unroll 8
  for (int m = 0; m < F; ++m) acc += wrow[m] * as[m * F + k];
  Wa[(s * F + i) * F + k] = acc;
}

// ---------------- kernel 1: [Wh|E1|E2] = h @ [W|Wa1|Wa2] ----------------
__global__ __launch_bounds__(256) void k_gemm(const float* __restrict__ h,
                                              const float* __restrict__ W,
                                              const float* __restrict__ Wa,
                                              float* __restrict__ Wh,
                                              float* __restrict__ E1,
                                              float* __restrict__ E2) {
  __shared__ float Alds[64][129];
  __shared__ float Blds[128][64];
  const int tid = threadIdx.x;
  const int rb = blockIdx.x * 64;
  const int matc = blockIdx.y >> 1;
  const int cb = (blockIdx.y & 1) * 64;

#pragma unroll
  for (int p = 0; p < 8; ++p) {
    int id = tid + p * 256;
    int row = id >> 5;
    int c0 = (id & 31) * 4;
    float4 v = *reinterpret_cast<const float4*>(&h[(rb + row) * F + c0]);
    Alds[row][c0 + 0] = v.x; Alds[row][c0 + 1] = v.y;
    Alds[row][c0 + 2] = v.z; Alds[row][c0 + 3] = v.w;
  }
  const float* src = (matc == 0) ? W : (Wa + (matc - 1) * F * F);
#pragma unroll
  for (int p = 0; p < 8; ++p) {
    int id = tid + p * 256;
    int k = id >> 4;
    int c0 = (id & 15) * 4;
    float4 v = *reinterpret_cast<const float4*>(&src[k * F + cb + c0]);
    Blds[k][c0 + 0] = v.x; Blds[k][c0 + 1] = v.y;
    Blds[k][c0 + 2] = v.z; Blds[k][c0 + 3] = v.w;
  }
  __syncthreads();

  const int tx = tid & 15;
  const int ty = tid >> 4;
  float acc[4][4] = {};
#pragma unroll 4
  for (int k = 0; k < 128; ++k) {
    float4 bv = *reinterpret_cast<const float4*>(&Blds[k][tx * 4]);
    float a0 = Alds[ty * 4 + 0][k];
    float a1 = Alds[ty * 4 + 1][k];
    float a2 = Alds[ty * 4 + 2][k];
    float a3 = Alds[ty * 4 + 3][k];
    acc[0][0] += a0 * bv.x; acc[0][1] += a0 * bv.y; acc[0][2] += a0 * bv.z; acc[0][3] += a0 * bv.w;
    acc[1][0] += a1 * bv.x; acc[1][1] += a1 * bv.y; acc[1][2] += a1 * bv.z; acc[1][3] += a1 * bv.w;
    acc[2][0] += a2 * bv.x; acc[2][1] += a2 * bv.y; acc[2][2] += a2 * bv.z; acc[2][3] += a2 * bv.w;
    acc[3][0] += a3 * bv.x; acc[3][1] += a3 * bv.y; acc[3][2] += a3 * bv.z; acc[3][3] += a3 * bv.w;
  }

  float* Dp = (matc == 0) ? Wh : ((matc == 1) ? E1 : E2);
  const int gr0 = rb + ty * 4;
  const int c0 = cb + tx * 4;
#pragma unroll
  for (int i = 0; i < 4; ++i) {
    float4 v;
    v.x = acc[i][0]; v.y = acc[i][1]; v.z = acc[i][2]; v.w = acc[i][3];
    *reinterpret_cast<float4*>(&Dp[(gr0 + i) * F + c0]) = v;
  }
}

// ------- kernel 2: fused attention, TWO rows (same t) per block -------
// grid 1280 = rows (2b, 2b+1), always same t-slice. Block 256 = 4 waves; wave w
// owns j-strip [w*32, w*32+32) for BOTH rows -> every E2/Wh load serves 2 rows.
// 5 blocks/CU, all co-resident (no tail). adj masks hoisted into ballots.
__global__ __launch_bounds__(256) void k_attn(const float* __restrict__ Wh,
                                              const float* __restrict__ E1,
                                              const float* __restrict__ E2,
                                              const float* __restrict__ adj,
                                              float* __restrict__ out,
                                              float* __restrict__ att) {
  __shared__ float sA[2][4][F];
  __shared__ float hA[2][4][F];
  __shared__ float invA[2][F];
  __shared__ float uniA[2];

  const int r0 = blockIdx.x * 2;          // even, so r0 and r0+1 share t
  const int r1 = r0 + 1;
  const int t = r0 >> 7;
  const int b0 = r0 & 127;
  const int w = threadIdx.x >> 6;
  const int lane = threadIdx.x & 63;
  const int fc = lane * 2;
  const int j0 = w * 32;

  const float* E2t = E2 + t * V * F;
  const float* Wht = Wh + t * V * F;
  const float* adj0 = adj + b0 * V;
  const float* adj1 = adj0 + V;

  // hoist adj for this wave's strip into two 32-bit masks (bit jj <-> j0+jj)
  const bool in32 = lane < 32;
  const unsigned long long Ma = __ballot(in32 ? (adj0[j0 + (lane & 31)] > 0.f) : false);
  const unsigned long long Mb = __ballot(in32 ? (adj1[j0 + (lane & 31)] > 0.f) : false);

  const float2 e1a = *reinterpret_cast<const float2*>(E1 + r0 * F + fc);
  const float2 e1b = *reinterpret_cast<const float2*>(E1 + r1 * F + fc);

  // ---- pass A: shared loads, per-row accumulate ----
  float sa0 = 0.f, sa1 = 0.f, ha0 = 0.f, ha1 = 0.f;
  float sb0 = 0.f, sb1 = 0.f, hb0 = 0.f, hb1 = 0.f;
#pragma unroll 4
  for (int jj = 0; jj < 32; ++jj) {
    const bool ta = (Ma >> jj) & 1;
    const bool tb = (Mb >> jj) & 1;
    if (ta | tb) {
      const int j = j0 + jj;
      float2 e2 = *reinterpret_cast<const float2*>(E2t + j * F + fc);
      float2 wv = *reinterpret_cast<const float2*>(Wht + j * F + fc);
      if (ta) {
        float x0 = e1a.x + e2.x, x1 = e1a.y + e2.y;
        x0 = x0 > 0.f ? x0 : ALPHA * x0;
        x1 = x1 > 0.f ? x1 : ALPHA * x1;
        float p0 = __expf(x0), p1 = __expf(x1);
        sa0 += p0; sa1 += p1; ha0 += p0 * wv.x; ha1 += p1 * wv.y;
      }
      if (tb) {
        float x0 = e1b.x + e2.x, x1 = e1b.y + e2.y;
        x0 = x0 > 0.f ? x0 : ALPHA * x0;
        x1 = x1 > 0.f ? x1 : ALPHA * x1;
        float p0 = __expf(x0), p1 = __expf(x1);
        sb0 += p0; sb1 += p1; hb0 += p0 * wv.x; hb1 += p1 * wv.y;
      }
    }
  }
  sA[0][w][fc] = sa0; sA[0][w][fc + 1] = sa1;
  hA[0][w][fc] = ha0; hA[0][w][fc + 1] = ha1;
  sA[1][w][fc] = sb0; sA[1][w][fc + 1] = sb1;
  hA[1][w][fc] = hb0; hA[1][w][fc + 1] = hb1;
  __syncthreads();

  // ---- reduce: wave 0 -> row 0, wave 1 -> row 1 (parallel) ----
  if (w < 2) {
    const int row = w;
    const int r = r0 + row;
    const float S0 = sA[row][0][fc] + sA[row][1][fc] + sA[row][2][fc] + sA[row][3][fc];
    const float S1 = sA[row][0][fc + 1] + sA[row][1][fc + 1] + sA[row][2][fc + 1] + sA[row][3][fc + 1];
    const bool uni = (S0 == 0.f);         // all-masked row -> uniform 1/V
    const float inv0 = uni ? (1.f / (float)V) : (1.f / S0);
    const float inv1 = uni ? (1.f / (float)V) : (1.f / S1);
    invA[row][fc] = inv0; invA[row][fc + 1] = inv1;
    if (lane == 0) uniA[row] = uni ? 1.f : 0.f;

    float H0, H1;
    if (uni) {
      H0 = 0.f; H1 = 0.f;
      for (int j = 0; j < V; ++j) {
        float2 wv = *reinterpret_cast<const float2*>(Wht + j * F + fc);
        H0 += wv.x; H1 += wv.y;
      }
      H0 *= inv0; H1 *= inv1;
    } else {
      H0 = (hA[row][0][fc] + hA[row][1][fc] + hA[row][2][fc] + hA[row][3][fc]) * inv0;
      H1 = (hA[row][0][fc + 1] + hA[row][1][fc + 1] + hA[row][2][fc + 1] + hA[row][3][fc + 1]) * inv1;
    }
    float2 ov;
    ov.x = H0 > 0.f ? H0 : __expf(H0) - 1.f;
    ov.y = H1 > 0.f ? H1 : __expf(H1) - 1.f;
    *reinterpret_cast<float2*>(out + r * F + fc) = ov;
  }
  __syncthreads();

  // ---- pass B: one e2q load feeds 2 stores (rows 0 and 1) ----
  const int jh = lane >> 5;
  const int f4 = (lane & 31) * 4;
  const float4 e1qa = *reinterpret_cast<const float4*>(E1 + r0 * F + f4);
  const float4 e1qb = *reinterpret_cast<const float4*>(E1 + r1 * F + f4);
  const float4 invqa = *reinterpret_cast<const float4*>(&invA[0][f4]);
  const float4 invqb = *reinterpret_cast<const float4*>(&invA[1][f4]);
  const bool ua = uniA[0] != 0.f;
  const bool ub = uniA[1] != 0.f;
  float* attb0 = att + (size_t)r0 * (V * F);
  float* attb1 = att + (size_t)r1 * (V * F);

#pragma unroll 4
  for (int jj = 0; jj < 16; ++jj) {
    const int j = j0 + jj * 2 + jh;
    const float4 e2q = *reinterpret_cast<const float4*>(E2t + j * F + f4);
    const float ga = (adj0[j] > 0.f) ? 1.f : 0.f;
    const float gb = (adj1[j] > 0.f) ? 1.f : 0.f;

    {
      float x0 = e1qa.x + e2q.x, x1 = e1qa.y + e2q.y;
      float x2 = e1qa.z + e2q.z, x3 = e1qa.w + e2q.w;
      x0 = x0 > 0.f ? x0 : ALPHA * x0;
      x1 = x1 > 0.f ? x1 : ALPHA * x1;
      x2 = x2 > 0.f ? x2 : ALPHA * x2;
      x3 = x3 > 0.f ? x3 : ALPHA * x3;
      float4 o;
      o.x = __expf(x0) * invqa.x * ga;
      o.y = __expf(x1) * invqa.y * ga;
      o.z = __expf(x2) * invqa.z * ga;
      o.w = __expf(x3) * invqa.w * ga;
      if (ua) { o.x = invqa.x; o.y = invqa.y; o.z = invqa.z; o.w = invqa.w; }
      *reinterpret_cast<float4*>(attb0 + j * F + f4) = o;
    }
    {
      float x0 = e1qb.x + e2q.x, x1 = e1qb.y + e2q.y;
      float x2 = e1qb.z + e2q.z, x3 = e1qb.w + e2q.w;
      x0 = x0 > 0.f ? x0 : ALPHA * x0;
      x1 = x1 > 0.f ? x1 : ALPHA * x1;
      x2 = x2 > 0.f ? x2 : ALPHA * x2;
      x3 = x3 > 0.f ? x3 : ALPHA * x3;
      float4 o;
      o.x = __expf(x0) * invqb.x * gb;
      o.y = __expf(x1) * invqb.y * gb;
      o.z = __expf(x2) * invqb.z * gb;
      o.w = __expf(x3) * invqb.w * gb;
      if (ub) { o.x = invqb.x; o.y = invqb.y; o.z = invqb.z; o.w = invqb.w; }
      *reinterpret_cast<float4*>(attb1 + j * F + f4) = o;
    }
  }
}

extern "C" void kernel_launch(void* const* d_in, const int* in_sizes, int n_in,
                              void* d_out, int out_size, void* d_ws, size_t ws_size,
                              hipStream_t stream) {
  (void)in_sizes; (void)n_in; (void)out_size; (void)ws_size;
  const float* h   = (const float*)d_in[0];
  const float* adj = (const float*)d_in[1];
  const float* W   = (const float*)d_in[2];
  const float* a   = (const float*)d_in[3];

  float* Wh = (float*)d_ws;
  float* E1 = Wh + NTIME * V * F;
  float* E2 = E1 + NTIME * V * F;
  float* Wa = E2 + NTIME * V * F;

  float* out = (float*)d_out;                    // (T, V, F)
  float* att = out + NTIME * V * F;              // (T, V, V, F)

  k_wa<<<dim3(128, 2), 128, 0, stream>>>(W, a, Wa);
  k_gemm<<<dim3(40, 6), 256, 0, stream>>>(h, W, Wa, Wh, E1, E2);
  k_attn<<<dim3(NTIME * V / 2), 256, 0, stream>>>(Wh, E1, E2, adj, out, att);
}